// Round 5
// baseline (1011.907 us; speedup 1.0000x reference)
//
#include <hip/hip_runtime.h>
#include <hip/hip_bf16.h>
#include <stdint.h>

#define B_   32768
#define JN   57
#define QSTR 256      // q row stride (228 padded to 256)

typedef _Float16 f16x8 __attribute__((ext_vector_type(8)));
typedef float    f32x4 __attribute__((ext_vector_type(4)));

__device__ __forceinline__ void split_f16(float v, _Float16& hi, _Float16& lo) {
  hi = (_Float16)v;
  lo = (_Float16)(v - (float)hi);
}

// ---------------- prep kernels ----------------
// x: [B_,171] f32 -> x2: [B_,384] f16  (cols 0..191 = hi, 192..383 = lo, zero-padded)
__global__ void prep_x2_kernel(const float* __restrict__ x, _Float16* __restrict__ xp) {
  long i = (long)blockIdx.x * 256 + threadIdx.x;   // over B_*192
  int row = (int)(i / 192), col = (int)(i % 192);
  float v = (col < 171) ? x[(long)row * 171 + col] : 0.f;
  _Float16 hi, lo; split_f16(v, hi, lo);
  xp[(long)row * 384 + col]       = hi;
  xp[(long)row * 384 + 192 + col] = lo;
}

// w: [Ksrc,Nsrc] f32 -> wf: [Ndst, 2*Kpad] f16 (B^T layout: hi plane | lo plane)
__global__ void prep_w2_kernel(const float* __restrict__ w, _Float16* __restrict__ wf,
                               int Ksrc, int Kpad, int Nsrc) {
  long i = (long)blockIdx.x * 256 + threadIdx.x;   // over Ndst*Kpad
  int n = (int)(i / Kpad), k = (int)(i % Kpad);
  float v = (k < Ksrc && n < Nsrc) ? w[(long)k * Nsrc + n] : 0.f;
  _Float16 hi, lo; split_f16(v, hi, lo);
  wf[(long)n * (2 * Kpad) + k]        = hi;
  wf[(long)n * (2 * Kpad) + Kpad + k] = lo;
}

__global__ void prep_b4_kernel(const float* __restrict__ b, float* __restrict__ bp) {
  int i = threadIdx.x;  // 256 threads
  bp[i] = (i < 228) ? b[i] : 0.f;
}

// ---------------- split-f16 GEMM: C = epi(A @ B^T + bias) ----------------
// A: [M, 2*Kp] f16 (hi|lo planes), Bt: [N, 2*Kp] f16 (hi|lo planes).
// Virtual K = 3*Kp: phase 0 = Ah*Bh, phase 1 = Ah*Bl, phase 2 = Al*Bh.
// 128x128 tile, BK=64, 4 waves, mfma_f32_16x16x32_f16 (m97 structure).
// T1 XCD-chunked swizzle: same-bm blocks land consecutively on one XCD so the
// shared A-panel is fetched into that XCD's L2 once (requires gridDim%8==0).
// EPI==0: f16 hi|lo out ([M,2N]) with bias+lrelu.  EPI==1: f32 out with bias.
template<int EPI>
__global__ __launch_bounds__(256)
void gemm_hl(const _Float16* __restrict__ A, const _Float16* __restrict__ Bt,
             const float* __restrict__ bias, void* __restrict__ Cout,
             int M, int N, int Kp)
{
  __shared__ __align__(16) _Float16 As[128 * 64];
  __shared__ __align__(16) _Float16 Bs[128 * 64];
  const int lda = 2 * Kp;
  const int T = Kp >> 6;
  const int tiles_n = N >> 7;
  // T1: hardware assigns XCD ~ blockIdx.x % 8; give each XCD a contiguous
  // bm-major chunk. Bijective since gridDim.x % 8 == 0.
  const int cpx  = gridDim.x >> 3;
  const int virt = (blockIdx.x & 7) * cpx + (blockIdx.x >> 3);
  const int bm = virt / tiles_n;
  const int bn = virt % tiles_n;
  const int tid  = threadIdx.x;
  const int wave = tid >> 6;
  const int lane = tid & 63;

  // staging geometry: each lane loads 16B (8 f16) per instruction
  const int srow = wave * 8 + (lane >> 3);   // +32 per i
  const int scol = (lane & 7) * 8;           // element col within 64-wide K slice
  const long abase = (long)bm * 128;
  const long bbase = (long)bn * 128;

  f32x4 acc[4][4] = {};

  const int wm = (wave >> 1) * 64;
  const int wn = (wave & 1) * 64;
  const int lr = lane & 15;          // A-row / B-col within 16x16 frag
  const int lk = (lane >> 4) * 8;    // k offset within 32

  for (int ph = 0; ph < 3; ++ph) {
    const int aoff = (ph == 2) ? Kp : 0;   // A: hi,hi,lo
    const int boff = (ph == 1) ? Kp : 0;   // B: hi,lo,hi
    for (int u = 0; u < T; ++u) {
#pragma unroll
      for (int i = 0; i < 4; i++) {
        const _Float16* asrc = A  + (abase + i * 32 + srow) * (long)lda + (aoff + u * 64 + scol);
        const _Float16* bsrc = Bt + (bbase + i * 32 + srow) * (long)lda + (boff + u * 64 + scol);
        __builtin_amdgcn_global_load_lds(
            (const __attribute__((address_space(1))) void*)asrc,
            (__attribute__((address_space(3))) void*)(As + (i * 256 + wave * 64) * 8),
            16, 0, 0);
        __builtin_amdgcn_global_load_lds(
            (const __attribute__((address_space(1))) void*)bsrc,
            (__attribute__((address_space(3))) void*)(Bs + (i * 256 + wave * 64) * 8),
            16, 0, 0);
      }
      __syncthreads();   // compiler emits vmcnt(0) drain before barrier

#pragma unroll
      for (int ks = 0; ks < 2; ks++) {
        f16x8 af[4], bfr[4];
#pragma unroll
        for (int m = 0; m < 4; m++)
          af[m] = *(const f16x8*)(As + (wm + m * 16 + lr) * 64 + ks * 32 + lk);
#pragma unroll
        for (int n = 0; n < 4; n++)
          bfr[n] = *(const f16x8*)(Bs + (wn + n * 16 + lr) * 64 + ks * 32 + lk);
#pragma unroll
        for (int m = 0; m < 4; m++)
#pragma unroll
          for (int n = 0; n < 4; n++)
            acc[m][n] = __builtin_amdgcn_mfma_f32_16x16x32_f16(af[m], bfr[n], acc[m][n], 0, 0, 0);
      }
      __syncthreads();
    }
  }

  // epilogue: C/D layout col=lane&15, row=(lane>>4)*4+reg  [m89-verified]
  const int crow0 = bm * 128 + wm + (lane >> 4) * 4;
  const int ccol0 = bn * 128 + wn + lr;
#pragma unroll
  for (int n = 0; n < 4; n++) {
    const int col = ccol0 + n * 16;
    const float bv = bias[col];
#pragma unroll
    for (int m = 0; m < 4; m++) {
#pragma unroll
      for (int r = 0; r < 4; r++) {
        float v = acc[m][n][r] + bv;
        const long row = crow0 + m * 16 + r;
        if (EPI == 0) {
          v = (v >= 0.f) ? v : 0.01f * v;
          _Float16 hi, lo; split_f16(v, hi, lo);
          _Float16* C = (_Float16*)Cout;
          C[row * (long)(2 * N) + col]     = hi;
          C[row * (long)(2 * N) + N + col] = lo;
        } else {
          ((float*)Cout)[row * (long)N + col] = v;
        }
      }
    }
  }
}

// ---------------- quat -> rotmat, write rot (d_out) + Lf (ws, f32) ----------------
// grid (B_/256, JN), block 256; lane = sample (coalesced Lf writes)
__global__ void quat_rot_kernel(const float* __restrict__ q, const float* __restrict__ offs,
                                float* __restrict__ rot, float* __restrict__ Lf)
{
  const int s = blockIdx.x * 256 + threadIdx.x;
  const int j = blockIdx.y;
  const float* qp = q + (long)s * QSTR + j * 4;
  float qw = qp[0], qx = qp[1], qy = qp[2], qz = qp[3];
  float n = sqrtf(qw * qw + qx * qx + qy * qy + qz * qz);
  n = fmaxf(n, 1e-8f);
  float inv = 1.f / n;
  qw *= inv; qx *= inv; qy *= inv; qz *= inv;
  const float xx = qx * qx, yy = qy * qy, zz = qz * qz;
  const float xy = qx * qy, xz = qx * qz, yz = qy * qz;
  const float xw = qx * qw, yw = qy * qw, zw = qz * qw;
  const float r00 = 1.f - 2.f * (yy + zz), r01 = 2.f * (xy - zw), r02 = 2.f * (xz + yw);
  const float r10 = 2.f * (xy + zw), r11 = 1.f - 2.f * (xx + zz), r12 = 2.f * (yz - xw);
  const float r20 = 2.f * (xz - yw), r21 = 2.f * (yz + xw), r22 = 1.f - 2.f * (xx + yy);

  float4* ro = (float4*)(rot + ((long)s * JN + j) * 16);
  ro[0] = make_float4(r00, r01, r02, 0.f);
  ro[1] = make_float4(r10, r11, r12, 0.f);
  ro[2] = make_float4(r20, r21, r22, 0.f);
  ro[3] = make_float4(0.f, 0.f, 0.f, 1.f);

  const float tx = offs[j * 3 + 0], ty = offs[j * 3 + 1], tz = offs[j * 3 + 2];
  float* L = Lf + (long)j * 12 * B_ + s;
  L[0L * B_]  = r00; L[1L * B_]  = r01; L[2L * B_]  = r02; L[3L * B_]  = tx;
  L[4L * B_]  = r10; L[5L * B_]  = r11; L[6L * B_]  = r12; L[7L * B_]  = ty;
  L[8L * B_]  = r20; L[9L * B_]  = r21; L[10L * B_] = r22; L[11L * B_] = tz;
}

// ---------------- forward kinematics (all fp32) ----------------
struct FkParams { int par[JN]; unsigned long long childmask; };

__global__ void fk_kernel(const float* __restrict__ Lf, float* __restrict__ Gt,
                          float* __restrict__ pose, FkParams P)
{
  const int s = blockIdx.x * 256 + threadIdx.x;
  float G[12];
#pragma unroll
  for (int e = 0; e < 12; e++) G[e] = Lf[(long)e * B_ + s];
  if (P.childmask & 1ull) {
#pragma unroll
    for (int e = 0; e < 12; e++) Gt[(long)e * B_ + s] = G[e];
  }
  pose[(long)s * (JN * 3) + 0] = G[3];
  pose[(long)s * (JN * 3) + 1] = G[7];
  pose[(long)s * (JN * 3) + 2] = G[11];

  for (int j = 1; j < JN; j++) {
    const int p = P.par[j];            // scalar -> uniform branch, no divergence
    float Pm[12];
    if (p == j - 1) {
#pragma unroll
      for (int e = 0; e < 12; e++) Pm[e] = G[e];
    } else {
#pragma unroll
      for (int e = 0; e < 12; e++) Pm[e] = Gt[((long)p * 12 + e) * B_ + s];
    }
    float L[12];
#pragma unroll
    for (int e = 0; e < 12; e++) L[e] = Lf[((long)j * 12 + e) * B_ + s];
#pragma unroll
    for (int r = 0; r < 3; r++) {
#pragma unroll
      for (int c = 0; c < 4; c++) {
        float v = Pm[r * 4 + 0] * L[0 * 4 + c] + Pm[r * 4 + 1] * L[1 * 4 + c]
                + Pm[r * 4 + 2] * L[2 * 4 + c];
        if (c == 3) v += Pm[r * 4 + 3];
        G[r * 4 + c] = v;   // safe: Pm holds parent copy
      }
    }
    if ((P.childmask >> j) & 1ull) {
#pragma unroll
      for (int e = 0; e < 12; e++) Gt[((long)j * 12 + e) * B_ + s] = G[e];
    }
    pose[(long)s * (JN * 3) + j * 3 + 0] = G[3];
    pose[(long)s * (JN * 3) + j * 3 + 1] = G[7];
    pose[(long)s * (JN * 3) + j * 3 + 2] = G[11];
  }
}

// ---------------- host: replicate np.random.default_rng(7) parents ----------------
// Verified against numpy bit_generator.pyx: hashmix/mix constants, INIT_A/B,
// MIX = (0xca01f9dd*x - 0x4973f715*y) ^>> 16  [subtraction],
// PCG64 XSL-RR 128/64 seeding, buffered next32, bounded_lemire_uint32.
static void compute_parents(int* par, unsigned long long* childmask)
{
  // SeedSequence(7), pool_size=4
  uint32_t pool[4];
  uint32_t hc = 0x43b0d7e5u;                       // INIT_A
  auto hashmix = [&hc](uint32_t v) {
    v ^= hc; hc *= 0x931e8875u; v *= hc; v ^= v >> 16; return v;
  };
  auto mix = [](uint32_t x, uint32_t y) {
    uint32_t r = 0xca01f9ddu * x - 0x4973f715u * y;   // MIX_MULT_L*x - MIX_MULT_R*y
    r ^= r >> 16;
    return r;
  };
  const uint32_t entropy[1] = {7u};
  for (int i = 0; i < 4; i++) pool[i] = hashmix(i < 1 ? entropy[i] : 0u);
  for (int si = 0; si < 4; si++)
    for (int di = 0; di < 4; di++)
      if (si != di) pool[di] = mix(pool[di], hashmix(pool[si]));
  // generate_state(4, uint64) -> 8x u32, LE-paired
  uint32_t gs[8];
  uint32_t hb = 0x8b51f9ddu;                       // INIT_B
  for (int i = 0; i < 8; i++) {
    uint32_t dv = pool[i & 3];
    dv ^= hb; hb *= 0x58f38dedu; dv *= hb; dv ^= dv >> 16;
    gs[i] = dv;
  }
  uint64_t sw0 = (uint64_t)gs[0] | ((uint64_t)gs[1] << 32);
  uint64_t sw1 = (uint64_t)gs[2] | ((uint64_t)gs[3] << 32);
  uint64_t iw0 = (uint64_t)gs[4] | ((uint64_t)gs[5] << 32);
  uint64_t iw1 = (uint64_t)gs[6] | ((uint64_t)gs[7] << 32);
  // PCG64 XSL-RR 128/64; PCG_128BIT_CONSTANT(high=word0, low=word1)
  const __uint128_t MULT = (((__uint128_t)0x2360ed051fc65da4ULL) << 64) | 0x4385df649fccf645ULL;
  __uint128_t inc = ((((__uint128_t)iw0 << 64) | iw1) << 1) | 1;
  __uint128_t state = 0;
  state = state * MULT + inc;
  state += (((__uint128_t)sw0) << 64) | sw1;
  state = state * MULT + inc;
  bool has32 = false; uint32_t buf32 = 0;
  auto next64 = [&]() {
    state = state * MULT + inc;
    uint64_t hi = (uint64_t)(state >> 64), lo = (uint64_t)state;
    uint32_t rot = (uint32_t)(state >> 122);
    uint64_t x = hi ^ lo;
    return (x >> rot) | (x << ((64u - rot) & 63u));
  };
  auto next32 = [&]() -> uint32_t {
    if (has32) { has32 = false; return buf32; }
    uint64_t v = next64();
    has32 = true; buf32 = (uint32_t)(v >> 32);
    return (uint32_t)v;
  };
  par[0] = -1;
  for (int j = 1; j < JN; j++) {
    uint32_t rng = (uint32_t)(j - 1);          // inclusive range of integers(0, j)
    if (rng == 0) { par[j] = 0; continue; }    // consumes no draws
    uint32_t rng_excl = rng + 1;               // Lemire 32 (numpy small-range fast path)
    uint64_t m = (uint64_t)next32() * (uint64_t)rng_excl;
    uint32_t leftover = (uint32_t)m;
    if (leftover < rng_excl) {
      uint32_t threshold = (uint32_t)((0x100000000ULL - rng_excl) % rng_excl);
      while (leftover < threshold) {
        m = (uint64_t)next32() * (uint64_t)rng_excl;
        leftover = (uint32_t)m;
      }
    }
    par[j] = (int)(m >> 32);
  }
  unsigned long long cm = 0;
  for (int j = 1; j < JN; j++) cm |= 1ull << par[j];
  *childmask = cm;
}

// ---------------- launch ----------------
extern "C" void kernel_launch(void* const* d_in, const int* in_sizes, int n_in,
                              void* d_out, int out_size, void* d_ws, size_t ws_size,
                              hipStream_t stream)
{
  const float* in_seq = (const float*)d_in[0];
  const float* w1 = (const float*)d_in[1];
  const float* b1 = (const float*)d_in[2];
  const float* w2 = (const float*)d_in[3];
  const float* b2 = (const float*)d_in[4];
  const float* w3 = (const float*)d_in[5];
  const float* b3 = (const float*)d_in[6];
  const float* w4 = (const float*)d_in[7];
  const float* b4 = (const float*)d_in[8];
  const float* offs = (const float*)d_in[9];

  // workspace layout (aliased; lifetimes verified):
  //  R1 @0        [35,390,464 B]: x2(25,165,824) w1f(786,432) w2f(4,194,304)
  //                               w3f(4,194,304) w4f(1,048,576) b4p(1,024)
  //                               later: q f32 (33,554,432) @0 — disjoint from w4f/b4p
  //  R2 @35,390,464  [134,217,728 B]: h1 -> h3 -> Gt(89,653,248)
  //  R3 @169,608,192 [134,217,728 B]: h2 -> Lf(89,653,248)
  char* pR1 = (char*)d_ws;
  char* pR2 = pR1 + 35390464;
  char* pR3 = pR2 + 134217728;
  _Float16* x2  = (_Float16*)pR1;
  _Float16* w1f = (_Float16*)(pR1 + 25165824);
  _Float16* w2f = (_Float16*)(pR1 + 25165824 + 786432);
  _Float16* w3f = (_Float16*)(pR1 + 25165824 + 786432 + 4194304);
  _Float16* w4f = (_Float16*)(pR1 + 25165824 + 786432 + 2 * 4194304);
  float*    b4p = (float*)(pR1 + 25165824 + 786432 + 2 * 4194304 + 1048576);
  float*    q   = (float*)pR1;            // overwrites x2/w1f/w2f/w3f only
  _Float16* h1  = (_Float16*)pR2;
  _Float16* h3  = (_Float16*)pR2;
  float*    Gt  = (float*)pR2;
  _Float16* h2  = (_Float16*)pR3;
  float*    Lf  = (float*)pR3;

  float* pose = (float*)d_out;                        // [B_,57,3]
  float* rot  = (float*)d_out + (long)B_ * JN * 3;    // [B_,57,4,4]

  // prep
  prep_x2_kernel<<<(B_ * 192) / 256, 256, 0, stream>>>(in_seq, x2);
  prep_w2_kernel<<<(1024 * 192) / 256, 256, 0, stream>>>(w1, w1f, 171, 192, 1024);
  prep_w2_kernel<<<(1024 * 1024) / 256, 256, 0, stream>>>(w2, w2f, 1024, 1024, 1024);
  prep_w2_kernel<<<(1024 * 1024) / 256, 256, 0, stream>>>(w3, w3f, 1024, 1024, 1024);
  prep_w2_kernel<<<(256 * 1024) / 256, 256, 0, stream>>>(w4, w4f, 1024, 1024, 228);
  prep_b4_kernel<<<1, 256, 0, stream>>>(b4, b4p);

  // MLP (split-f16, virtual 3K)
  gemm_hl<0><<<(B_ / 128) * (1024 / 128), 256, 0, stream>>>(x2, w1f, b1, h1, B_, 1024, 192);
  gemm_hl<0><<<(B_ / 128) * (1024 / 128), 256, 0, stream>>>(h1, w2f, b2, h2, B_, 1024, 1024);
  gemm_hl<0><<<(B_ / 128) * (1024 / 128), 256, 0, stream>>>(h2, w3f, b3, h3, B_, 1024, 1024);
  gemm_hl<1><<<(B_ / 128) * (QSTR / 128), 256, 0, stream>>>(h3, w4f, b4p, q, B_, QSTR, 1024);

  // epilogue
  quat_rot_kernel<<<dim3(B_ / 256, JN), 256, 0, stream>>>(q, offs, rot, Lf);

  FkParams P;
  compute_parents(P.par, &P.childmask);
  fk_kernel<<<B_ / 256, 256, 0, stream>>>(Lf, Gt, pose, P);
}

// Round 6
// 881.125 us; speedup vs baseline: 1.1484x; 1.1484x over previous
//
#include <hip/hip_runtime.h>
#include <hip/hip_bf16.h>
#include <stdint.h>

#define B_   32768
#define JN   57
#define QSTR 256      // q row stride (228 padded to 256)

typedef _Float16 f16x8 __attribute__((ext_vector_type(8)));
typedef float    f32x4 __attribute__((ext_vector_type(4)));

__device__ __forceinline__ void split_f16(float v, _Float16& hi, _Float16& lo) {
  hi = (_Float16)v;
  lo = (_Float16)(v - (float)hi);
}

// ---------------- prep kernels ----------------
// x: [B_,171] f32 -> x2: [B_,384] f16  (cols 0..191 = hi, 192..383 = lo, zero-padded)
__global__ void prep_x2_kernel(const float* __restrict__ x, _Float16* __restrict__ xp) {
  long i = (long)blockIdx.x * 256 + threadIdx.x;   // over B_*192
  int row = (int)(i / 192), col = (int)(i % 192);
  float v = (col < 171) ? x[(long)row * 171 + col] : 0.f;
  _Float16 hi, lo; split_f16(v, hi, lo);
  xp[(long)row * 384 + col]       = hi;
  xp[(long)row * 384 + 192 + col] = lo;
}

// w: [Ksrc,Nsrc] f32 -> wf: [Ndst, 2*Kpad] f16 (B^T layout: hi plane | lo plane)
__global__ void prep_w2_kernel(const float* __restrict__ w, _Float16* __restrict__ wf,
                               int Ksrc, int Kpad, int Nsrc) {
  long i = (long)blockIdx.x * 256 + threadIdx.x;   // over Ndst*Kpad
  int n = (int)(i / Kpad), k = (int)(i % Kpad);
  float v = (k < Ksrc && n < Nsrc) ? w[(long)k * Nsrc + n] : 0.f;
  _Float16 hi, lo; split_f16(v, hi, lo);
  wf[(long)n * (2 * Kpad) + k]        = hi;
  wf[(long)n * (2 * Kpad) + Kpad + k] = lo;
}

__global__ void prep_b4_kernel(const float* __restrict__ b, float* __restrict__ bp) {
  int i = threadIdx.x;  // 256 threads
  bp[i] = (i < 228) ? b[i] : 0.f;
}

// ---------------- split-f16 GEMM: C = epi(A @ B^T + bias) ----------------
// A: [M, 2*Kp] f16 (hi|lo planes), Bt: [N, 2*Kp] f16 (hi|lo planes).
// Virtual K = 3*Kp: phase 0 = Ah*Bh, phase 1 = Ah*Bl, phase 2 = Al*Bh.
// 128x128 tile, BK=64, 4 waves, mfma_f32_16x16x32_f16 (m97 structure).
// T1 XCD-chunked swizzle (bijective; gridDim%8==0).
// T2 LDS swizzle (rule #21: linear global_load_lds dest + inverse-swizzled
// global SOURCE + swizzled read): 16B-chunk index ^= (row&7). Kills the
// 16-way bank conflict of 128B-stride rows (bank = chunk only, row drops out).
// EPI==0: f16 hi|lo out ([M,2N]) with bias+lrelu.  EPI==1: f32 out with bias.
template<int EPI>
__global__ __launch_bounds__(256)
void gemm_hl(const _Float16* __restrict__ A, const _Float16* __restrict__ Bt,
             const float* __restrict__ bias, void* __restrict__ Cout,
             int M, int N, int Kp)
{
  __shared__ __align__(16) _Float16 As[128 * 64];
  __shared__ __align__(16) _Float16 Bs[128 * 64];
  const int lda = 2 * Kp;
  const int T = Kp >> 6;
  const int tiles_n = N >> 7;
  const int cpx  = gridDim.x >> 3;
  const int virt = (blockIdx.x & 7) * cpx + (blockIdx.x >> 3);
  const int bm = virt / tiles_n;
  const int bn = virt % tiles_n;
  const int tid  = threadIdx.x;
  const int wave = tid >> 6;
  const int lane = tid & 63;

  // staging geometry: lane loads 16B; LDS dest linear (base + lane*16).
  // Source col chunk pre-swizzled: chunk' = (lane&7) ^ (lds_row&7), and
  // lds_row&7 == lane>>3 here (row base wave*8 + i*32 keeps mod-8 = lane>>3).
  const int srow = wave * 8 + (lane >> 3);                    // +32 per i
  const int scol = (((lane & 7) ^ (lane >> 3)) * 8);          // swizzled source col (f16)
  const long abase = (long)bm * 128;
  const long bbase = (long)bn * 128;

  f32x4 acc[4][4] = {};

  const int wm = (wave >> 1) * 64;
  const int wn = (wave & 1) * 64;
  const int lr = lane & 15;          // A-row / B-col within 16x16 frag
  // swizzled read chunk offsets (f16 elems): chunk = (ks*4 + lane>>4) ^ (row&7),
  // row&7 == lr&7 == lane&7 for all frag rows (wm, m*16 are multiples of 8).
  const int ch0 = (((lane >> 4) ^ (lane & 7)) * 8);           // ks=0
  const int ch1 = (((4 + (lane >> 4)) ^ (lane & 7)) * 8);     // ks=1

  for (int ph = 0; ph < 3; ++ph) {
    const int aoff = (ph == 2) ? Kp : 0;   // A: hi,hi,lo
    const int boff = (ph == 1) ? Kp : 0;   // B: hi,lo,hi
    for (int u = 0; u < T; ++u) {
#pragma unroll
      for (int i = 0; i < 4; i++) {
        const _Float16* asrc = A  + (abase + i * 32 + srow) * (long)lda + (aoff + u * 64 + scol);
        const _Float16* bsrc = Bt + (bbase + i * 32 + srow) * (long)lda + (boff + u * 64 + scol);
        __builtin_amdgcn_global_load_lds(
            (const __attribute__((address_space(1))) void*)asrc,
            (__attribute__((address_space(3))) void*)(As + (i * 256 + wave * 64) * 8),
            16, 0, 0);
        __builtin_amdgcn_global_load_lds(
            (const __attribute__((address_space(1))) void*)bsrc,
            (__attribute__((address_space(3))) void*)(Bs + (i * 256 + wave * 64) * 8),
            16, 0, 0);
      }
      __syncthreads();   // compiler emits vmcnt(0) drain before barrier

#pragma unroll
      for (int ks = 0; ks < 2; ks++) {
        const int ch = ks ? ch1 : ch0;
        f16x8 af[4], bfr[4];
#pragma unroll
        for (int m = 0; m < 4; m++)
          af[m] = *(const f16x8*)(As + (wm + m * 16 + lr) * 64 + ch);
#pragma unroll
        for (int n = 0; n < 4; n++)
          bfr[n] = *(const f16x8*)(Bs + (wn + n * 16 + lr) * 64 + ch);
#pragma unroll
        for (int m = 0; m < 4; m++)
#pragma unroll
          for (int n = 0; n < 4; n++)
            acc[m][n] = __builtin_amdgcn_mfma_f32_16x16x32_f16(af[m], bfr[n], acc[m][n], 0, 0, 0);
      }
      __syncthreads();
    }
  }

  // epilogue: C/D layout col=lane&15, row=(lane>>4)*4+reg  [m89-verified]
  const int crow0 = bm * 128 + wm + (lane >> 4) * 4;
  const int ccol0 = bn * 128 + wn + lr;
#pragma unroll
  for (int n = 0; n < 4; n++) {
    const int col = ccol0 + n * 16;
    const float bv = bias[col];
#pragma unroll
    for (int m = 0; m < 4; m++) {
#pragma unroll
      for (int r = 0; r < 4; r++) {
        float v = acc[m][n][r] + bv;
        const long row = crow0 + m * 16 + r;
        if (EPI == 0) {
          v = (v >= 0.f) ? v : 0.01f * v;
          _Float16 hi, lo; split_f16(v, hi, lo);
          _Float16* C = (_Float16*)Cout;
          C[row * (long)(2 * N) + col]     = hi;
          C[row * (long)(2 * N) + N + col] = lo;
        } else {
          ((float*)Cout)[row * (long)N + col] = v;
        }
      }
    }
  }
}

// ---------------- quat -> rotmat, write rot (d_out) + Lf (ws, f32) ----------------
// grid (B_/256, JN), block 256; lane = sample (coalesced Lf writes)
__global__ void quat_rot_kernel(const float* __restrict__ q, const float* __restrict__ offs,
                                float* __restrict__ rot, float* __restrict__ Lf)
{
  const int s = blockIdx.x * 256 + threadIdx.x;
  const int j = blockIdx.y;
  const float* qp = q + (long)s * QSTR + j * 4;
  float qw = qp[0], qx = qp[1], qy = qp[2], qz = qp[3];
  float n = sqrtf(qw * qw + qx * qx + qy * qy + qz * qz);
  n = fmaxf(n, 1e-8f);
  float inv = 1.f / n;
  qw *= inv; qx *= inv; qy *= inv; qz *= inv;
  const float xx = qx * qx, yy = qy * qy, zz = qz * qz;
  const float xy = qx * qy, xz = qx * qz, yz = qy * qz;
  const float xw = qx * qw, yw = qy * qw, zw = qz * qw;
  const float r00 = 1.f - 2.f * (yy + zz), r01 = 2.f * (xy - zw), r02 = 2.f * (xz + yw);
  const float r10 = 2.f * (xy + zw), r11 = 1.f - 2.f * (xx + zz), r12 = 2.f * (yz - xw);
  const float r20 = 2.f * (xz - yw), r21 = 2.f * (yz + xw), r22 = 1.f - 2.f * (xx + yy);

  float4* ro = (float4*)(rot + ((long)s * JN + j) * 16);
  ro[0] = make_float4(r00, r01, r02, 0.f);
  ro[1] = make_float4(r10, r11, r12, 0.f);
  ro[2] = make_float4(r20, r21, r22, 0.f);
  ro[3] = make_float4(0.f, 0.f, 0.f, 1.f);

  const float tx = offs[j * 3 + 0], ty = offs[j * 3 + 1], tz = offs[j * 3 + 2];
  float* L = Lf + (long)j * 12 * B_ + s;
  L[0L * B_]  = r00; L[1L * B_]  = r01; L[2L * B_]  = r02; L[3L * B_]  = tx;
  L[4L * B_]  = r10; L[5L * B_]  = r11; L[6L * B_]  = r12; L[7L * B_]  = ty;
  L[8L * B_]  = r20; L[9L * B_]  = r21; L[10L * B_] = r22; L[11L * B_] = tz;
}

// ---------------- forward kinematics (all fp32) ----------------
struct FkParams { int par[JN]; unsigned long long childmask; };

__global__ void fk_kernel(const float* __restrict__ Lf, float* __restrict__ Gt,
                          float* __restrict__ pose, FkParams P)
{
  const int s = blockIdx.x * 256 + threadIdx.x;
  float G[12];
#pragma unroll
  for (int e = 0; e < 12; e++) G[e] = Lf[(long)e * B_ + s];
  if (P.childmask & 1ull) {
#pragma unroll
    for (int e = 0; e < 12; e++) Gt[(long)e * B_ + s] = G[e];
  }
  pose[(long)s * (JN * 3) + 0] = G[3];
  pose[(long)s * (JN * 3) + 1] = G[7];
  pose[(long)s * (JN * 3) + 2] = G[11];

  for (int j = 1; j < JN; j++) {
    const int p = P.par[j];            // scalar -> uniform branch, no divergence
    float Pm[12];
    if (p == j - 1) {
#pragma unroll
      for (int e = 0; e < 12; e++) Pm[e] = G[e];
    } else {
#pragma unroll
      for (int e = 0; e < 12; e++) Pm[e] = Gt[((long)p * 12 + e) * B_ + s];
    }
    float L[12];
#pragma unroll
    for (int e = 0; e < 12; e++) L[e] = Lf[((long)j * 12 + e) * B_ + s];
#pragma unroll
    for (int r = 0; r < 3; r++) {
#pragma unroll
      for (int c = 0; c < 4; c++) {
        float v = Pm[r * 4 + 0] * L[0 * 4 + c] + Pm[r * 4 + 1] * L[1 * 4 + c]
                + Pm[r * 4 + 2] * L[2 * 4 + c];
        if (c == 3) v += Pm[r * 4 + 3];
        G[r * 4 + c] = v;   // safe: Pm holds parent copy
      }
    }
    if ((P.childmask >> j) & 1ull) {
#pragma unroll
      for (int e = 0; e < 12; e++) Gt[((long)j * 12 + e) * B_ + s] = G[e];
    }
    pose[(long)s * (JN * 3) + j * 3 + 0] = G[3];
    pose[(long)s * (JN * 3) + j * 3 + 1] = G[7];
    pose[(long)s * (JN * 3) + j * 3 + 2] = G[11];
  }
}

// ---------------- host: replicate np.random.default_rng(7) parents ----------------
// Verified against numpy bit_generator.pyx: hashmix/mix constants, INIT_A/B,
// MIX = (0xca01f9dd*x - 0x4973f715*y) ^>> 16  [subtraction],
// PCG64 XSL-RR 128/64 seeding, buffered next32, bounded_lemire_uint32.
static void compute_parents(int* par, unsigned long long* childmask)
{
  // SeedSequence(7), pool_size=4
  uint32_t pool[4];
  uint32_t hc = 0x43b0d7e5u;                       // INIT_A
  auto hashmix = [&hc](uint32_t v) {
    v ^= hc; hc *= 0x931e8875u; v *= hc; v ^= v >> 16; return v;
  };
  auto mix = [](uint32_t x, uint32_t y) {
    uint32_t r = 0xca01f9ddu * x - 0x4973f715u * y;   // MIX_MULT_L*x - MIX_MULT_R*y
    r ^= r >> 16;
    return r;
  };
  const uint32_t entropy[1] = {7u};
  for (int i = 0; i < 4; i++) pool[i] = hashmix(i < 1 ? entropy[i] : 0u);
  for (int si = 0; si < 4; si++)
    for (int di = 0; di < 4; di++)
      if (si != di) pool[di] = mix(pool[di], hashmix(pool[si]));
  // generate_state(4, uint64) -> 8x u32, LE-paired
  uint32_t gs[8];
  uint32_t hb = 0x8b51f9ddu;                       // INIT_B
  for (int i = 0; i < 8; i++) {
    uint32_t dv = pool[i & 3];
    dv ^= hb; hb *= 0x58f38dedu; dv *= hb; dv ^= dv >> 16;
    gs[i] = dv;
  }
  uint64_t sw0 = (uint64_t)gs[0] | ((uint64_t)gs[1] << 32);
  uint64_t sw1 = (uint64_t)gs[2] | ((uint64_t)gs[3] << 32);
  uint64_t iw0 = (uint64_t)gs[4] | ((uint64_t)gs[5] << 32);
  uint64_t iw1 = (uint64_t)gs[6] | ((uint64_t)gs[7] << 32);
  // PCG64 XSL-RR 128/64; PCG_128BIT_CONSTANT(high=word0, low=word1)
  const __uint128_t MULT = (((__uint128_t)0x2360ed051fc65da4ULL) << 64) | 0x4385df649fccf645ULL;
  __uint128_t inc = ((((__uint128_t)iw0 << 64) | iw1) << 1) | 1;
  __uint128_t state = 0;
  state = state * MULT + inc;
  state += (((__uint128_t)sw0) << 64) | sw1;
  state = state * MULT + inc;
  bool has32 = false; uint32_t buf32 = 0;
  auto next64 = [&]() {
    state = state * MULT + inc;
    uint64_t hi = (uint64_t)(state >> 64), lo = (uint64_t)state;
    uint32_t rot = (uint32_t)(state >> 122);
    uint64_t x = hi ^ lo;
    return (x >> rot) | (x << ((64u - rot) & 63u));
  };
  auto next32 = [&]() -> uint32_t {
    if (has32) { has32 = false; return buf32; }
    uint64_t v = next64();
    has32 = true; buf32 = (uint32_t)(v >> 32);
    return (uint32_t)v;
  };
  par[0] = -1;
  for (int j = 1; j < JN; j++) {
    uint32_t rng = (uint32_t)(j - 1);          // inclusive range of integers(0, j)
    if (rng == 0) { par[j] = 0; continue; }    // consumes no draws
    uint32_t rng_excl = rng + 1;               // Lemire 32 (numpy small-range fast path)
    uint64_t m = (uint64_t)next32() * (uint64_t)rng_excl;
    uint32_t leftover = (uint32_t)m;
    if (leftover < rng_excl) {
      uint32_t threshold = (uint32_t)((0x100000000ULL - rng_excl) % rng_excl);
      while (leftover < threshold) {
        m = (uint64_t)next32() * (uint64_t)rng_excl;
        leftover = (uint32_t)m;
      }
    }
    par[j] = (int)(m >> 32);
  }
  unsigned long long cm = 0;
  for (int j = 1; j < JN; j++) cm |= 1ull << par[j];
  *childmask = cm;
}

// ---------------- launch ----------------
extern "C" void kernel_launch(void* const* d_in, const int* in_sizes, int n_in,
                              void* d_out, int out_size, void* d_ws, size_t ws_size,
                              hipStream_t stream)
{
  const float* in_seq = (const float*)d_in[0];
  const float* w1 = (const float*)d_in[1];
  const float* b1 = (const float*)d_in[2];
  const float* w2 = (const float*)d_in[3];
  const float* b2 = (const float*)d_in[4];
  const float* w3 = (const float*)d_in[5];
  const float* b3 = (const float*)d_in[6];
  const float* w4 = (const float*)d_in[7];
  const float* b4 = (const float*)d_in[8];
  const float* offs = (const float*)d_in[9];

  // workspace layout (aliased; lifetimes verified):
  //  R1 @0        [35,390,464 B]: x2(25,165,824) w1f(786,432) w2f(4,194,304)
  //                               w3f(4,194,304) w4f(1,048,576) b4p(1,024)
  //                               later: q f32 (33,554,432) @0 — disjoint from w4f/b4p
  //  R2 @35,390,464  [134,217,728 B]: h1 -> h3 -> Gt(89,653,248)
  //  R3 @169,608,192 [134,217,728 B]: h2 -> Lf(89,653,248)
  char* pR1 = (char*)d_ws;
  char* pR2 = pR1 + 35390464;
  char* pR3 = pR2 + 134217728;
  _Float16* x2  = (_Float16*)pR1;
  _Float16* w1f = (_Float16*)(pR1 + 25165824);
  _Float16* w2f = (_Float16*)(pR1 + 25165824 + 786432);
  _Float16* w3f = (_Float16*)(pR1 + 25165824 + 786432 + 4194304);
  _Float16* w4f = (_Float16*)(pR1 + 25165824 + 786432 + 2 * 4194304);
  float*    b4p = (float*)(pR1 + 25165824 + 786432 + 2 * 4194304 + 1048576);
  float*    q   = (float*)pR1;            // overwrites x2/w1f/w2f/w3f only
  _Float16* h1  = (_Float16*)pR2;
  _Float16* h3  = (_Float16*)pR2;
  float*    Gt  = (float*)pR2;
  _Float16* h2  = (_Float16*)pR3;
  float*    Lf  = (float*)pR3;

  float* pose = (float*)d_out;                        // [B_,57,3]
  float* rot  = (float*)d_out + (long)B_ * JN * 3;    // [B_,57,4,4]

  // prep
  prep_x2_kernel<<<(B_ * 192) / 256, 256, 0, stream>>>(in_seq, x2);
  prep_w2_kernel<<<(1024 * 192) / 256, 256, 0, stream>>>(w1, w1f, 171, 192, 1024);
  prep_w2_kernel<<<(1024 * 1024) / 256, 256, 0, stream>>>(w2, w2f, 1024, 1024, 1024);
  prep_w2_kernel<<<(1024 * 1024) / 256, 256, 0, stream>>>(w3, w3f, 1024, 1024, 1024);
  prep_w2_kernel<<<(256 * 1024) / 256, 256, 0, stream>>>(w4, w4f, 1024, 1024, 228);
  prep_b4_kernel<<<1, 256, 0, stream>>>(b4, b4p);

  // MLP (split-f16, virtual 3K)
  gemm_hl<0><<<(B_ / 128) * (1024 / 128), 256, 0, stream>>>(x2, w1f, b1, h1, B_, 1024, 192);
  gemm_hl<0><<<(B_ / 128) * (1024 / 128), 256, 0, stream>>>(h1, w2f, b2, h2, B_, 1024, 1024);
  gemm_hl<0><<<(B_ / 128) * (1024 / 128), 256, 0, stream>>>(h2, w3f, b3, h3, B_, 1024, 1024);
  gemm_hl<1><<<(B_ / 128) * (QSTR / 128), 256, 0, stream>>>(h3, w4f, b4p, q, B_, QSTR, 1024);

  // epilogue
  quat_rot_kernel<<<dim3(B_ / 256, JN), 256, 0, stream>>>(q, offs, rot, Lf);

  FkParams P;
  compute_parents(P.par, &P.childmask);
  fk_kernel<<<B_ / 256, 256, 0, stream>>>(Lf, Gt, pose, P);
}